// Round 5
// baseline (546.171 us; speedup 1.0000x reference)
//
#include <hip/hip_runtime.h>
#include <hip/hip_cooperative_groups.h>

namespace cg = cooperative_groups;

#define BV 518
#define SS 2048
#define NB 32
#define NCOL (NB * SS)   // 65536 columns
#define NBLK 1024
#define NTHR 256

__device__ inline void tok_meta(int id, int& ty, float& val) {
    int base;
    if (id < 128)      { ty = 0; base = 0; }
    else if (id < 289) { ty = 1; base = 128; }
    else if (id < 390) { ty = 2; base = 289; }
    else               { ty = 3; base = 390; }
    val = (float)(id - base);
}

// Single fused cooperative kernel.
// ws layout (floats): [0..63] acc ; [64..] lse_row (16576, pad to 16640) ;
// then pse[4*NCOL], pbs[4*NCOL], pbi[4*NCOL] (as int).
__global__ __launch_bounds__(NTHR, 4) void fused_kernel(const float* __restrict__ logits,
                                                        const int* __restrict__ target,
                                                        float* __restrict__ ws,
                                                        float* __restrict__ out) {
    float* acc     = ws;
    float* lse_row = ws + 64;
    float* pse     = ws + 64 + 16640;
    float* pbs     = pse + 4 * NCOL;
    int*   pbi     = (int*)(pbs + 4 * NCOL);

    const int t   = threadIdx.x;
    const int bid = blockIdx.x;
    cg::grid_group grid = cg::this_grid();

    __shared__ float cse[4][256];
    __shared__ float cbs[4][256];
    __shared__ int   cbi[4][256];
    __shared__ float slse[544];

    // ---- Phase A: per-(b,v) row logsumexp. One wave per row (8 indep float4/lane).
    {
        const int wave = bid * 4 + (t >> 6);     // 4096 waves
        const int lane = t & 63;
        for (int row = wave; row < NB * BV; row += 4 * NBLK) {
            const float4* b4 = (const float4*)(logits + (size_t)row * SS);
            float s = 0.f;
            #pragma unroll
            for (int i = 0; i < 8; ++i) {
                float4 x = b4[lane + 64 * i];
                s += __expf(x.x) + __expf(x.y) + __expf(x.z) + __expf(x.w);
            }
            #pragma unroll
            for (int off = 32; off; off >>= 1) s += __shfl_down(s, off);
            if (lane == 0) lse_row[row] = __logf(s);
        }
    }
    grid.sync();

    // ---- Phase B: partial column pass. bid = b*32 + stile*4 + q.
    {
        const int q     = bid & 3;
        const int stile = (bid >> 2) & 7;
        const int b     = bid >> 5;
        for (int i = t; i < BV; i += NTHR) slse[i] = lse_row[b * BV + i];
        __syncthreads();

        const int lane = t & 63;
        const int part = t >> 6;
        const int fidx = stile * 64 + lane;                 // float4 index in row
        const float4* rowbase = (const float4*)(logits + (size_t)b * BV * SS);

        const int vqs = (BV * q) >> 2;        // 0,129,259,388
        const int vqe = (BV * (q + 1)) >> 2;  // 129,259,388,518

        float4 se = make_float4(0.f, 0.f, 0.f, 0.f);
        float4 bs = make_float4(-1e30f, -1e30f, -1e30f, -1e30f);
        int bix = 0x7fffffff, biy = 0x7fffffff, biz = 0x7fffffff, biw = 0x7fffffff;

        #pragma unroll 4
        for (int v = vqs + part; v < vqe; v += 4) {
            float4 x = rowbase[(size_t)v * (SS / 4) + fidx];
            float l = slse[v];
            se.x += __expf(x.x); se.y += __expf(x.y);
            se.z += __expf(x.z); se.w += __expf(x.w);
            float c0 = x.x - l, c1 = x.y - l, c2 = x.z - l, c3 = x.w - l;
            if (c0 > bs.x) { bs.x = c0; bix = v; }   // strict > keeps lowest v
            if (c1 > bs.y) { bs.y = c1; biy = v; }
            if (c2 > bs.z) { bs.z = c2; biz = v; }
            if (c3 > bs.w) { bs.w = c3; biw = v; }
        }

        const int sb = lane * 4;
        cse[part][sb]     = se.x;  cse[part][sb + 1] = se.y;
        cse[part][sb + 2] = se.z;  cse[part][sb + 3] = se.w;
        cbs[part][sb]     = bs.x;  cbs[part][sb + 1] = bs.y;
        cbs[part][sb + 2] = bs.z;  cbs[part][sb + 3] = bs.w;
        cbi[part][sb]     = bix;   cbi[part][sb + 1] = biy;
        cbi[part][sb + 2] = biz;   cbi[part][sb + 3] = biw;
        __syncthreads();

        float tot = 0.f, best = -1e30f;
        int   bi  = 0x7fffffff;
        #pragma unroll
        for (int p = 0; p < 4; ++p) {
            tot += cse[p][t];
            float s2 = cbs[p][t]; int i2 = cbi[p][t];
            if (s2 > best || (s2 == best && i2 < bi)) { best = s2; bi = i2; }
        }
        const int g = b * SS + stile * 256 + t;
        pse[q * NCOL + g] = tot;
        pbs[q * NCOL + g] = best;
        pbi[q * NCOL + g] = bi;
    }
    grid.sync();

    // ---- Phase C: combine quarters, gather target logit, nll+mask, reduce.
    if (bid < NCOL / NTHR) {
        const int g = bid * NTHR + t;
        const int b = g >> 11;
        const int s = g & 2047;

        float tot = 0.f, best = -1e30f;
        int   bi  = 0x7fffffff;
        #pragma unroll
        for (int q = 0; q < 4; ++q) {
            tot += pse[q * NCOL + g];
            float s2 = pbs[q * NCOL + g]; int i2 = pbi[q * NCOL + g];
            if (s2 > best) { best = s2; bi = i2; }   // quarters in ascending v
        }

        const int tgt = target[g];
        const float ot = logits[(size_t)(b * BV + tgt) * SS + s];
        float nll = __logf(tot) - ot;

        int pt_, tt_; float pv_, tv_;
        tok_meta(bi, pt_, pv_);
        tok_meta(tgt, tt_, tv_);
        float mask;
        if (pt_ != tt_) {
            mask = 1.0f;
        } else if (pt_ == 0) {
            mask = 0.5f;                              // pitch branch: constant coef
        } else {
            float dn = (pt_ == 1) ? 160.f : ((pt_ == 2) ? 100.f : 128.f);
            mask = 0.5f * fabsf(pv_ - tv_) / dn;
        }

        #pragma unroll
        for (int off = 32; off; off >>= 1) {
            nll  += __shfl_down(nll, off);
            mask += __shfl_down(mask, off);
        }
        if ((t & 63) == 0) { cse[0][t >> 6] = nll; cbs[0][t >> 6] = mask; }
        __syncthreads();
        if (t == 0) {
            atomicAdd(&acc[0], cse[0][0] + cse[0][1] + cse[0][2] + cse[0][3]);
            atomicAdd(&acc[1], cbs[0][0] + cbs[0][1] + cbs[0][2] + cbs[0][3]);
        }
    }
    grid.sync();

    if (bid == 0 && t == 0) {
        const float invN = 1.0f / (float)NCOL;
        float loss = acc[0] * invN;
        float mm   = acc[1] * invN;
        out[0] = loss * (1.0f + mm);
    }
}

extern "C" void kernel_launch(void* const* d_in, const int* in_sizes, int n_in,
                              void* d_out, int out_size, void* d_ws, size_t ws_size,
                              hipStream_t stream) {
    const float* logits = (const float*)d_in[0];
    const int*   target = (const int*)d_in[1];
    float* outp = (float*)d_out;
    float* ws   = (float*)d_ws;

    hipMemsetAsync(d_ws, 0, 64, stream);

    void* args[] = { (void*)&logits, (void*)&target, (void*)&ws, (void*)&outp };
    hipLaunchCooperativeKernel((const void*)fused_kernel, dim3(NBLK), dim3(NTHR),
                               args, 0, stream);
}

// Round 9
// 223.626 us; speedup vs baseline: 2.4423x; 2.4423x over previous
//
#include <hip/hip_runtime.h>

#define BV 518
#define SS 2048
#define NB 32
#define NCOL (NB * SS)   // 65536 columns
#define NQ 8             // v-chunks

__device__ inline void tok_meta(int id, int& ty, float& val) {
    int base;
    if (id < 128)      { ty = 0; base = 0; }
    else if (id < 289) { ty = 1; base = 128; }
    else if (id < 390) { ty = 2; base = 289; }
    else               { ty = 3; base = 390; }
    val = (float)(id - base);
}

// Kernel 1: per-(b,v) row logsumexp over S (no max subtraction; inputs ~N(0,1))
__global__ __launch_bounds__(256) void row_lse_kernel(const float* __restrict__ logits,
                                                      float* __restrict__ lse_row) {
    const int row = blockIdx.x;                       // b*518 + v
    const float4* base4 = (const float4*)(logits + (size_t)row * SS);
    const int t = threadIdx.x;
    float4 x0 = base4[t];
    float4 x1 = base4[t + 256];
    float s = __expf(x0.x) + __expf(x0.y) + __expf(x0.z) + __expf(x0.w)
            + __expf(x1.x) + __expf(x1.y) + __expf(x1.z) + __expf(x1.w);
    #pragma unroll
    for (int off = 32; off; off >>= 1) s += __shfl_down(s, off);
    __shared__ float ws[4];
    if ((t & 63) == 0) ws[t >> 6] = s;
    __syncthreads();
    if (t == 0) lse_row[row] = __logf(ws[0] + ws[1] + ws[2] + ws[3]);
}

// Kernel 2: partial column pass. bid = b*64 + stile*8 + q.
// 256 thr = 4 v-partitions x 64 lanes; lane owns 4 consecutive s (float4).
// Two independent row-streams per lane + explicit rotating prefetch -> 4+ loads in flight.
// 2048 blocks = 8 blocks/CU = 32 waves/CU.
__global__ __launch_bounds__(256, 8) void col_partial_kernel(const float* __restrict__ logits,
                                                             const float* __restrict__ lse_row,
                                                             float* __restrict__ pse,
                                                             float* __restrict__ pbs,
                                                             int*   __restrict__ pbi) {
    const int bid   = blockIdx.x;
    const int q     = bid & 7;
    const int stile = (bid >> 3) & 7;
    const int b     = bid >> 6;
    const int t     = threadIdx.x;
    const int lane  = t & 63;
    const int part  = t >> 6;            // 0..3

    __shared__ float slse[544];
    for (int i = t; i < BV; i += 256) slse[i] = lse_row[b * BV + i];
    __syncthreads();

    const int fidx = stile * 64 + lane;                 // float4 index within a row
    const float4* rowbase = (const float4*)(logits + (size_t)b * BV * SS);

    const int vqs = (BV * q) >> 3;        // chunk [vqs, vqe)
    const int vqe = (BV * (q + 1)) >> 3;

    float4 se = make_float4(0.f, 0.f, 0.f, 0.f);
    float4 bs = make_float4(-1e30f, -1e30f, -1e30f, -1e30f);
    int bix = 0x7fffffff, biy = 0x7fffffff, biz = 0x7fffffff, biw = 0x7fffffff;

#define PROC(X, V)                                                        \
    {                                                                     \
        float l = slse[(V)];                                              \
        se.x += __expf((X).x); se.y += __expf((X).y);                     \
        se.z += __expf((X).z); se.w += __expf((X).w);                     \
        float c0 = (X).x - l, c1 = (X).y - l, c2 = (X).z - l, c3 = (X).w - l; \
        if (c0 > bs.x) { bs.x = c0; bix = (V); }                          \
        if (c1 > bs.y) { bs.y = c1; biy = (V); }                          \
        if (c2 > bs.z) { bs.z = c2; biz = (V); }                          \
        if (c3 > bs.w) { bs.w = c3; biw = (V); }                          \
    }

    // rows for this part: v = vqs+part, step 4; K rows total (>=16)
    const int K = (vqe - vqs - part + 3) >> 2;
    int v = vqs + part;
    const int vlast = vqs + part + 4 * (K - 1);
    // prime two streams
    float4 x0 = rowbase[(size_t)v * (SS / 4) + fidx];
    int v1c = (v + 4 <= vlast) ? v + 4 : vlast;
    float4 x1 = rowbase[(size_t)v1c * (SS / 4) + fidx];
    int k = 0;
    while (k + 2 <= K) {
        int n0c = (v + 8  <= vlast) ? v + 8  : vlast;   // clamped unconditional prefetch
        int n1c = (v + 12 <= vlast) ? v + 12 : vlast;
        float4 n0 = rowbase[(size_t)n0c * (SS / 4) + fidx];
        float4 n1 = rowbase[(size_t)n1c * (SS / 4) + fidx];
        PROC(x0, v);
        PROC(x1, v + 4);
        x0 = n0; x1 = n1;
        v += 8; k += 2;
    }
    if (k < K) PROC(x0, v);
#undef PROC

    __shared__ float cse[4][256];
    __shared__ float cbs[4][256];
    __shared__ int   cbi[4][256];
    const int sb = lane * 4;
    cse[part][sb]     = se.x;  cse[part][sb + 1] = se.y;
    cse[part][sb + 2] = se.z;  cse[part][sb + 3] = se.w;
    cbs[part][sb]     = bs.x;  cbs[part][sb + 1] = bs.y;
    cbs[part][sb + 2] = bs.z;  cbs[part][sb + 3] = bs.w;
    cbi[part][sb]     = bix;   cbi[part][sb + 1] = biy;
    cbi[part][sb + 2] = biz;   cbi[part][sb + 3] = biw;
    __syncthreads();

    float tot = 0.f, best = -1e30f;
    int   bi  = 0x7fffffff;
    #pragma unroll
    for (int p = 0; p < 4; ++p) {
        tot += cse[p][t];
        float s2 = cbs[p][t]; int i2 = cbi[p][t];
        if (s2 > best || (s2 == best && i2 < bi)) { best = s2; bi = i2; }  // lowest-v tie-break
    }
    const int g = b * SS + stile * 256 + t;   // global column id
    pse[q * NCOL + g] = tot;
    pbs[q * NCOL + g] = best;
    pbi[q * NCOL + g] = bi;
}

// Kernel 3: combine the 8 v-chunks, gather target logit, nll+mask, reduce.
__global__ __launch_bounds__(256) void combine_kernel(const float* __restrict__ logits,
                                                      const int* __restrict__ target,
                                                      const float* __restrict__ pse,
                                                      const float* __restrict__ pbs,
                                                      const int* __restrict__ pbi,
                                                      float* __restrict__ acc) {
    const int t = threadIdx.x;
    const int g = blockIdx.x * 256 + t;      // 0..65535
    const int b = g >> 11;
    const int s = g & 2047;

    float tot = 0.f, best = -1e30f;
    int   bi  = 0x7fffffff;
    #pragma unroll
    for (int q = 0; q < NQ; ++q) {
        tot += pse[q * NCOL + g];
        float s2 = pbs[q * NCOL + g]; int i2 = pbi[q * NCOL + g];
        if (s2 > best) { best = s2; bi = i2; }   // chunks ascend in v; strict > keeps lowest
    }

    const int tgt = target[g];
    const float ot = logits[(size_t)(b * BV + tgt) * SS + s];   // L3-hot gather
    float nll = __logf(tot) - ot;

    int pt_, tt_; float pv_, tv_;
    tok_meta(bi, pt_, pv_);
    tok_meta(tgt, tt_, tv_);
    float mask;
    if (pt_ != tt_) {
        mask = 1.0f;
    } else if (pt_ == 0) {
        mask = 0.5f;                          // pitch branch: constant coef
    } else {
        float dn = (pt_ == 1) ? 160.f : ((pt_ == 2) ? 100.f : 128.f);
        mask = 0.5f * fabsf(pv_ - tv_) / dn;
    }

    #pragma unroll
    for (int off = 32; off; off >>= 1) {
        nll  += __shfl_down(nll, off);
        mask += __shfl_down(mask, off);
    }
    __shared__ float wn[4], wm[4];
    if ((t & 63) == 0) { wn[t >> 6] = nll; wm[t >> 6] = mask; }
    __syncthreads();
    if (t == 0) {
        atomicAdd(&acc[0], wn[0] + wn[1] + wn[2] + wn[3]);
        atomicAdd(&acc[1], wm[0] + wm[1] + wm[2] + wm[3]);
    }
}

__global__ void finalize_kernel(const float* __restrict__ acc, float* __restrict__ out) {
    const float invN = 1.0f / (float)(NB * SS);
    float loss = acc[0] * invN;
    float mm   = acc[1] * invN;
    out[0] = loss * (1.0f + mm);
}

extern "C" void kernel_launch(void* const* d_in, const int* in_sizes, int n_in,
                              void* d_out, int out_size, void* d_ws, size_t ws_size,
                              hipStream_t stream) {
    const float* logits = (const float*)d_in[0];
    const int*   target = (const int*)d_in[1];
    float* outp = (float*)d_out;

    float* acc     = (float*)d_ws;                  // 2 floats (zeroed below)
    float* lse_row = (float*)d_ws + 64;             // 32*518 = 16576 floats (pad to 16640)
    float* pse     = (float*)d_ws + 64 + 16640;     // 8*65536 floats
    float* pbs     = pse + NQ * NCOL;               // 8*65536 floats
    int*   pbi     = (int*)(pbs + NQ * NCOL);       // 8*65536 ints

    hipMemsetAsync(d_ws, 0, 64, stream);
    row_lse_kernel<<<NB * BV, 256, 0, stream>>>(logits, lse_row);
    col_partial_kernel<<<NB * 64, 256, 0, stream>>>(logits, lse_row, pse, pbs, pbi);
    combine_kernel<<<NCOL / 256, 256, 0, stream>>>(logits, target, pse, pbs, pbi, acc);
    finalize_kernel<<<1, 1, 0, stream>>>(acc, outp);
}

// Round 10
// 212.276 us; speedup vs baseline: 2.5729x; 1.0535x over previous
//
#include <hip/hip_runtime.h>

#define BV 518
#define SS 2048
#define NB 32
#define NCOL (NB * SS)   // 65536 columns
#define CHUNK 16
#define NCH 33           // ceil(518/16); last chunk has 6 rows

__device__ inline void tok_meta(int id, int& ty, float& val) {
    int base;
    if (id < 128)      { ty = 0; base = 0; }
    else if (id < 289) { ty = 1; base = 128; }
    else if (id < 390) { ty = 2; base = 289; }
    else               { ty = 3; base = 390; }
    val = (float)(id - base);
}

// Single-HBM-pass kernel. Block = (b, 16-row v-chunk). For each 4-row sub-chunk:
// wave w streams row w (coalesced float4, 8 indep loads/lane), computes exact
// row-LSE locally; then all 256 threads re-read the L2-hot 32KB column-wise
// (thread t owns s = t+256u) scoring argmax(x - lse) + sumexp into registers.
// Chunk results merged across blocks via device atomics (add f32 / max u64).
// __launch_bounds__(256,2): 2 blocks/CU so live sub-chunks (2MB/XCD) stay in L2.
__global__ __launch_bounds__(256, 2) void colfused_kernel(const float* __restrict__ logits,
                                                          float* __restrict__ sacc,
                                                          unsigned long long* __restrict__ pmax) {
    const int bid = blockIdx.x;
    const int b   = bid / NCH;
    const int c   = bid % NCH;
    const int v0  = c * CHUNK;
    const int nrows = (BV - v0 < CHUNK) ? (BV - v0) : CHUNK;
    const int t = threadIdx.x;
    const int w = t >> 6;        // wave id 0..3
    const int l = t & 63;        // lane

    __shared__ float slse[2][4];
    const float* base = logits + (size_t)(b * BV) * SS;

    float se[8];  float bsc[8];  int bvi[8];
    #pragma unroll
    for (int u = 0; u < 8; ++u) { se[u] = 0.f; bsc[u] = -1e30f; bvi[u] = 0; }

    const int nsub = (nrows + 3) >> 2;
    for (int sub = 0; sub < nsub; ++sub) {
        const int r0 = sub * 4;
        const int myrow = r0 + w;
        if (myrow < nrows) {
            const float4* rb = (const float4*)(base + (size_t)(v0 + myrow) * SS);
            float s = 0.f;
            #pragma unroll
            for (int j = 0; j < 8; ++j) {        // 8 independent 16B loads in flight
                float4 x = rb[l + 64 * j];
                s += __expf(x.x) + __expf(x.y) + __expf(x.z) + __expf(x.w);
            }
            #pragma unroll
            for (int off = 32; off; off >>= 1) s += __shfl_xor(s, off);
            if (l == 0) slse[sub & 1][w] = __logf(s);
        }
        __syncthreads();                          // lse ready; 2-slot alternation avoids WAR

        const int rend = (nrows - r0 < 4) ? (nrows - r0) : 4;
        for (int r = 0; r < rend; ++r) {
            const int v = v0 + r0 + r;
            const float lse = slse[sub & 1][r];
            const float* rowp = base + (size_t)v * SS;
            #pragma unroll
            for (int u = 0; u < 8; ++u) {         // L2-hot, coalesced (consecutive lanes->consecutive s)
                float x = rowp[u * 256 + t];
                se[u] += __expf(x);
                float sc = x - lse;
                if (sc > bsc[u]) { bsc[u] = sc; bvi[u] = v; }   // strict > keeps lowest v
            }
        }
    }

    // merge this chunk into global per-column accumulators
    #pragma unroll
    for (int u = 0; u < 8; ++u) {
        const int g = b * SS + u * 256 + t;
        atomicAdd(&sacc[g], se[u]);
        unsigned int ub = __float_as_uint(bsc[u]);
        ub = (ub & 0x80000000u) ? ~ub : (ub | 0x80000000u);          // order-preserving f32->u32
        unsigned long long packed = ((unsigned long long)ub << 32)
                                  | (unsigned long long)(0xFFFFu - (unsigned)bvi[u]); // tie -> lower v
        atomicMax(&pmax[g], packed);
    }
}

// Per-column finish: nll from summed exps, unpack argmax, gather target logit,
// mask, block-level reduction to per-block partials (no same-address atomics).
__global__ __launch_bounds__(256) void combine_kernel(const float* __restrict__ logits,
                                                      const int* __restrict__ target,
                                                      const float* __restrict__ sacc,
                                                      const unsigned long long* __restrict__ pmax,
                                                      float* __restrict__ pnll,
                                                      float* __restrict__ pmask) {
    const int t = threadIdx.x;
    const int g = blockIdx.x * 256 + t;      // 0..65535
    const int b = g >> 11;
    const int s = g & 2047;

    const float tot = sacc[g];
    const unsigned long long p = pmax[g];
    const int bi  = 0xFFFF - (int)(p & 0xFFFFull);
    const int tgt = target[g];
    const float ot = logits[(size_t)(b * BV + tgt) * SS + s];   // L3-hot gather
    float nll = __logf(tot) - ot;

    int pt_, tt_; float pv_, tv_;
    tok_meta(bi, pt_, pv_);
    tok_meta(tgt, tt_, tv_);
    float mask;
    if (pt_ != tt_) {
        mask = 1.0f;
    } else if (pt_ == 0) {
        mask = 0.5f;                          // pitch branch: constant coef
    } else {
        float dn = (pt_ == 1) ? 160.f : ((pt_ == 2) ? 100.f : 128.f);
        mask = 0.5f * fabsf(pv_ - tv_) / dn;
    }

    #pragma unroll
    for (int off = 32; off; off >>= 1) {
        nll  += __shfl_down(nll, off);
        mask += __shfl_down(mask, off);
    }
    __shared__ float wn[4], wm[4];
    if ((t & 63) == 0) { wn[t >> 6] = nll; wm[t >> 6] = mask; }
    __syncthreads();
    if (t == 0) {
        pnll[blockIdx.x]  = wn[0] + wn[1] + wn[2] + wn[3];
        pmask[blockIdx.x] = wm[0] + wm[1] + wm[2] + wm[3];
    }
}

// Reduce 256 block-partials and write the scalar result.
__global__ __launch_bounds__(256) void finalize_kernel(const float* __restrict__ pnll,
                                                       const float* __restrict__ pmask,
                                                       float* __restrict__ out) {
    const int t = threadIdx.x;
    float n = pnll[t];
    float m = pmask[t];
    #pragma unroll
    for (int off = 32; off; off >>= 1) {
        n += __shfl_down(n, off);
        m += __shfl_down(m, off);
    }
    __shared__ float wn[4], wm[4];
    if ((t & 63) == 0) { wn[t >> 6] = n; wm[t >> 6] = m; }
    __syncthreads();
    if (t == 0) {
        const float invN = 1.0f / (float)NCOL;
        float loss = (wn[0] + wn[1] + wn[2] + wn[3]) * invN;
        float mm   = (wm[0] + wm[1] + wm[2] + wm[3]) * invN;
        out[0] = loss * (1.0f + mm);
    }
}

extern "C" void kernel_launch(void* const* d_in, const int* in_sizes, int n_in,
                              void* d_out, int out_size, void* d_ws, size_t ws_size,
                              hipStream_t stream) {
    const float* logits = (const float*)d_in[0];
    const int*   target = (const int*)d_in[1];
    float* outp = (float*)d_out;

    // ws layout (bytes): [0,256K) sacc f32[65536]; [256K,768K) pmax u64[65536];
    // [768K,769K) pnll f32[256]; [769K,770K) pmask f32[256]
    float*              sacc  = (float*)d_ws;
    unsigned long long* pmax  = (unsigned long long*)((char*)d_ws + (NCOL * 4));
    float*              pnll  = (float*)((char*)d_ws + (NCOL * 12));
    float*              pmask = pnll + 256;

    hipMemsetAsync(d_ws, 0, NCOL * 12, stream);   // zero sacc + pmax
    colfused_kernel<<<NB * NCH, 256, 0, stream>>>(logits, sacc, pmax);
    combine_kernel<<<NCOL / 256, 256, 0, stream>>>(logits, target, sacc, pmax, pnll, pmask);
    finalize_kernel<<<1, 256, 0, stream>>>(pnll, pmask, outp);
}